// Round 1
// baseline (260.374 us; speedup 1.0000x reference)
//
#include <hip/hip_runtime.h>

#define TPB 256

// ---- workspace layout (float offsets) ----
// xf     : 0         (80*4096)   downsampled fast, [c][n], n = t*1024+h*32+w
// xs     : 327680    (80*4096)   downsampled slow
// theta  : 655360    (4096*40)   [n][o]
// phi    : 819200    (4096*40)   [m][o]
// gx     : 983040    (4096*40)   [m][o]
// ypart  : 1146880   (32*4096*40) [chunk][n][o]
// spart  : 6389760   (32*4096)
// yfin   : 6520832   (40*4096)   [o][n]
// z      : 6684672   (80*4096)
// total  : 7012352 floats = 28.05 MB

// ---------------- downsample 64 -> 32 (4-tap antialiased linear) ----------
__device__ __forceinline__ void taps_down(int i, int* j, float* w) {
    if (i == 0) {
        j[0]=0; j[1]=0; j[2]=1; j[3]=2;
        w[0]=0.f; w[1]=3.f/7.f; w[2]=3.f/7.f; w[3]=1.f/7.f;
    } else if (i == 31) {
        j[0]=61; j[1]=62; j[2]=63; j[3]=63;
        w[0]=1.f/7.f; w[1]=3.f/7.f; w[2]=3.f/7.f; w[3]=0.f;
    } else {
        j[0]=2*i-1; j[1]=2*i; j[2]=2*i+1; j[3]=2*i+2;
        w[0]=0.125f; w[1]=0.375f; w[2]=0.375f; w[3]=0.125f;
    }
}

__global__ __launch_bounds__(TPB) void k_downsample(
        const float* __restrict__ fast, const float* __restrict__ slow,
        float* __restrict__ xf, float* __restrict__ xs) {
    int idx = blockIdx.x * TPB + threadIdx.x;   // 0 .. 655359
    int which = idx >= 327680;
    int rem = which ? idx - 327680 : idx;
    const float* src = which ? slow : fast;
    float* dst = which ? xs : xf;
    int c = rem >> 12;
    int n = rem & 4095;
    int tt = n >> 10, hh = (n >> 5) & 31, ww = n & 31;
    int jy[4], jx[4]; float wy[4], wx[4];
    taps_down(hh, jy, wy);
    taps_down(ww, jx, wx);
    const float* base = src + ((c * 4 + tt) << 12);   // 64*64 plane
    float acc = 0.f;
#pragma unroll
    for (int a = 0; a < 4; ++a) {
        const float* row = base + (jy[a] << 6);
        float r = wx[0]*row[jx[0]] + wx[1]*row[jx[1]] + wx[2]*row[jx[2]] + wx[3]*row[jx[3]];
        acc += wy[a] * r;
    }
    dst[rem] = acc;
}

// ---------------- projections: theta/phi/gx = W @ xf + b -----------------
__global__ __launch_bounds__(TPB) void k_project(
        const float* __restrict__ xf,
        const float* __restrict__ gw, const float* __restrict__ gb,
        const float* __restrict__ thw, const float* __restrict__ thb,
        const float* __restrict__ phw, const float* __restrict__ phb,
        float* __restrict__ theta, float* __restrict__ phi, float* __restrict__ gx) {
    __shared__ float s_g[3200], s_th[3200], s_ph[3200], s_b[120];
    int t = threadIdx.x;
    for (int i = t; i < 3200; i += TPB) { s_g[i]=gw[i]; s_th[i]=thw[i]; s_ph[i]=phw[i]; }
    if (t < 40) { s_b[t]=gb[t]; s_b[40+t]=thb[t]; s_b[80+t]=phb[t]; }
    __syncthreads();
    int n = blockIdx.x * TPB + t;
    float x[80];
#pragma unroll
    for (int c = 0; c < 80; ++c) x[c] = xf[c*4096 + n];
    for (int o = 0; o < 40; ++o) {
        float ag = s_b[o], at = s_b[40+o], ap = s_b[80+o];
        const float* rg = &s_g[o*80];
        const float* rt = &s_th[o*80];
        const float* rp = &s_ph[o*80];
#pragma unroll
        for (int c = 0; c < 80; ++c) {
            float xv = x[c];
            ag += rg[c]*xv; at += rt[c]*xv; ap += rp[c]*xv;
        }
        gx[n*40+o] = ag; theta[n*40+o] = at; phi[n*40+o] = ap;
    }
}

// ---------------- fused attention: partial exp-weighted sums -------------
// grid (16 rowblocks, 32 m-chunks); thread owns row n; chunk = 128 m's.
__global__ __launch_bounds__(TPB) void k_attn(
        const float* __restrict__ theta, const float* __restrict__ phi,
        const float* __restrict__ gx,
        float* __restrict__ ypart, float* __restrict__ spart) {
    __shared__ float phs[64*40];
    __shared__ float gxs[64*40];
    int t = threadIdx.x;
    int n = blockIdx.x * TPB + t;
    int ck = blockIdx.y;
    float4 th[10];
    const float4* thp = (const float4*)(theta + n*40);
#pragma unroll
    for (int k = 0; k < 10; ++k) th[k] = thp[k];
    float4 acc[10];
#pragma unroll
    for (int k = 0; k < 10; ++k) acc[k] = make_float4(0.f,0.f,0.f,0.f);
    float s = 0.f;
    int m0c = ck * 128;
    for (int tile = 0; tile < 2; ++tile) {
        int m0 = m0c + tile * 64;
        for (int i = t; i < 2560; i += TPB) {
            phs[i] = phi[m0*40 + i];
            gxs[i] = gx[m0*40 + i];
        }
        __syncthreads();
        for (int j = 0; j < 64; ++j) {
            const float4* pr = (const float4*)(phs + j*40);   // wave-uniform -> broadcast
            float4 f4 = make_float4(0.f,0.f,0.f,0.f);
#pragma unroll
            for (int k = 0; k < 10; ++k) {
                float4 p = pr[k]; float4 a = th[k];
                f4.x += a.x*p.x; f4.y += a.y*p.y; f4.z += a.z*p.z; f4.w += a.w*p.w;
            }
            float f = (f4.x + f4.y) + (f4.z + f4.w);
            float e = __expf(f);   // |f| << 20: no max-subtraction needed
            s += e;
            const float4* gr = (const float4*)(gxs + j*40);
#pragma unroll
            for (int k = 0; k < 10; ++k) {
                float4 g = gr[k];
                acc[k].x += e*g.x; acc[k].y += e*g.y; acc[k].z += e*g.z; acc[k].w += e*g.w;
            }
        }
        __syncthreads();
    }
    float4* yp = (float4*)(ypart + (ck*4096 + n)*40);
#pragma unroll
    for (int k = 0; k < 10; ++k) yp[k] = acc[k];
    spart[ck*4096 + n] = s;
}

// ---------------- combine partials: yfin[o][n] = sum(ypart)/sum(spart) ---
__global__ __launch_bounds__(TPB) void k_combine(
        const float* __restrict__ ypart, const float* __restrict__ spart,
        float* __restrict__ yfin) {
    int n = blockIdx.x * TPB + threadIdx.x;
    float st = 0.f;
#pragma unroll
    for (int sc = 0; sc < 32; ++sc) st += spart[sc*4096 + n];
    float inv = 1.f / st;
    float4 acc[10];
#pragma unroll
    for (int k = 0; k < 10; ++k) acc[k] = make_float4(0.f,0.f,0.f,0.f);
    for (int sc = 0; sc < 32; ++sc) {
        const float4* rp = (const float4*)(ypart + ((size_t)(sc*4096 + n))*40);
#pragma unroll
        for (int k = 0; k < 10; ++k) {
            float4 v = rp[k];
            acc[k].x += v.x; acc[k].y += v.y; acc[k].z += v.z; acc[k].w += v.w;
        }
    }
#pragma unroll
    for (int k = 0; k < 10; ++k) {
        yfin[(4*k+0)*4096 + n] = acc[k].x * inv;
        yfin[(4*k+1)*4096 + n] = acc[k].y * inv;
        yfin[(4*k+2)*4096 + n] = acc[k].z * inv;
        yfin[(4*k+3)*4096 + n] = acc[k].w * inv;
    }
}

// ---------------- wz projection + BatchNorm + multiply by x_slow ---------
__global__ __launch_bounds__(TPB) void k_bn(
        const float* __restrict__ yfin, const float* __restrict__ wzw,
        const float* __restrict__ wzb, const float* __restrict__ bng,
        const float* __restrict__ bnb, const float* __restrict__ xs,
        float* __restrict__ z) {
    __shared__ float wrow[4096];
    __shared__ float red[TPB];
    int ch = blockIdx.x;
    int t = threadIdx.x;
    float w[40];
#pragma unroll
    for (int o = 0; o < 40; ++o) w[o] = wzw[ch*40 + o];
    float bias = wzb[ch];
    float s1 = 0.f, s2 = 0.f;
    for (int n = t; n < 4096; n += TPB) {
        float a = bias;
#pragma unroll
        for (int o = 0; o < 40; ++o) a += w[o] * yfin[o*4096 + n];
        wrow[n] = a;
        s1 += a; s2 += a*a;
    }
    red[t] = s1; __syncthreads();
    for (int off = TPB/2; off > 0; off >>= 1) {
        if (t < off) red[t] += red[t + off];
        __syncthreads();
    }
    float mean = red[0] * (1.f/4096.f);
    __syncthreads();
    red[t] = s2; __syncthreads();
    for (int off = TPB/2; off > 0; off >>= 1) {
        if (t < off) red[t] += red[t + off];
        __syncthreads();
    }
    float var = red[0] * (1.f/4096.f) - mean*mean;
    float inv = rsqrtf(var + 1e-5f);
    float sc = bng[ch] * inv;
    float sh = bnb[ch] - mean * sc;
    for (int n = t; n < 4096; n += TPB) {
        z[ch*4096 + n] = (wrow[n]*sc + sh) * xs[ch*4096 + n];
    }
}

// ---------------- upsample 32 -> 64 (2-tap linear) -----------------------
__device__ __forceinline__ void taps_up(int i, int* j0, int* j1, float* w0, float* w1) {
    if (i == 0)        { *j0 = 0;        *j1 = 0;          *w0 = 0.f;   *w1 = 1.f;   }
    else if (i == 63)  { *j0 = 31;       *j1 = 31;         *w0 = 1.f;   *w1 = 0.f;   }
    else if (i & 1)    { *j0 = i >> 1;   *j1 = (i>>1) + 1; *w0 = 0.75f; *w1 = 0.25f; }
    else               { *j0 = (i>>1)-1; *j1 = i >> 1;     *w0 = 0.25f; *w1 = 0.75f; }
}

__global__ __launch_bounds__(TPB) void k_upsample(
        const float* __restrict__ z, float* __restrict__ out) {
    int idx = blockIdx.x * TPB + threadIdx.x;   // 0 .. 1310719
    int x = idx & 63;
    int y = (idx >> 6) & 63;
    int ct = idx >> 12;                         // c*4 + t, 0..319
    int jy0, jy1, jx0, jx1; float wy0, wy1, wx0, wx1;
    taps_up(y, &jy0, &jy1, &wy0, &wy1);
    taps_up(x, &jx0, &jx1, &wx0, &wx1);
    const float* base = z + (ct << 10);         // 32*32 plane
    float r0 = wx0*base[jy0*32 + jx0] + wx1*base[jy0*32 + jx1];
    float r1 = wx0*base[jy1*32 + jx0] + wx1*base[jy1*32 + jx1];
    out[idx] = wy0*r0 + wy1*r1;
}

extern "C" void kernel_launch(void* const* d_in, const int* in_sizes, int n_in,
                              void* d_out, int out_size, void* d_ws, size_t ws_size,
                              hipStream_t stream) {
    const float* fast = (const float*)d_in[0];
    const float* slow = (const float*)d_in[1];
    const float* g_w  = (const float*)d_in[2];
    const float* g_b  = (const float*)d_in[3];
    const float* th_w = (const float*)d_in[4];
    const float* th_b = (const float*)d_in[5];
    const float* ph_w = (const float*)d_in[6];
    const float* ph_b = (const float*)d_in[7];
    const float* wz_w = (const float*)d_in[8];
    const float* wz_b = (const float*)d_in[9];
    const float* bn_g = (const float*)d_in[10];
    const float* bn_b = (const float*)d_in[11];
    float* out = (float*)d_out;
    float* ws  = (float*)d_ws;

    float* xf    = ws;
    float* xs    = ws + 327680;
    float* theta = ws + 655360;
    float* phi   = ws + 819200;
    float* gx    = ws + 983040;
    float* ypart = ws + 1146880;
    float* spart = ws + 6389760;
    float* yfin  = ws + 6520832;
    float* z     = ws + 6684672;

    k_downsample<<<2560, TPB, 0, stream>>>(fast, slow, xf, xs);
    k_project<<<16, TPB, 0, stream>>>(xf, g_w, g_b, th_w, th_b, ph_w, ph_b, theta, phi, gx);
    k_attn<<<dim3(16, 32), TPB, 0, stream>>>(theta, phi, gx, ypart, spart);
    k_combine<<<16, TPB, 0, stream>>>(ypart, spart, yfin);
    k_bn<<<80, TPB, 0, stream>>>(yfin, wz_w, wz_b, bn_g, bn_b, xs, z);
    k_upsample<<<5120, TPB, 0, stream>>>(z, out);
}

// Round 3
// 178.238 us; speedup vs baseline: 1.4608x; 1.4608x over previous
//
#include <hip/hip_runtime.h>

#define TPB 256

// ---- workspace layout (float offsets) ----
// xf     : 0        (327680)  downsampled fast, [c][n]
// xs     : 327680   (327680)  downsampled slow, [c][n]
// thetaT : 655360   (163840)  [o][n]
// phiT   : 819200   (163840)  [o][m]
// gxT    : 983040   (163840)  [o][m]
// ypart  : 1146880  (2621440) [chunk(16)][n][o]
// spart  : 3768320  (65536)   [chunk][n]
// yfin   : 3833856  (163840)  [o][n]
// total 3997696 floats = 16.0 MB

// ---------------- downsample 64 -> 32 (4-tap antialiased linear) ----------
__device__ __forceinline__ void taps_down(int i, int* j, float* w) {
    if (i == 0) {
        j[0]=0; j[1]=0; j[2]=1; j[3]=2;
        w[0]=0.f; w[1]=3.f/7.f; w[2]=3.f/7.f; w[3]=1.f/7.f;
    } else if (i == 31) {
        j[0]=61; j[1]=62; j[2]=63; j[3]=63;
        w[0]=1.f/7.f; w[1]=3.f/7.f; w[2]=3.f/7.f; w[3]=0.f;
    } else {
        j[0]=2*i-1; j[1]=2*i; j[2]=2*i+1; j[3]=2*i+2;
        w[0]=0.125f; w[1]=0.375f; w[2]=0.375f; w[3]=0.125f;
    }
}

__global__ __launch_bounds__(TPB) void k_downsample(
        const float* __restrict__ fast, const float* __restrict__ slow,
        float* __restrict__ xf, float* __restrict__ xs) {
    int idx = blockIdx.x * TPB + threadIdx.x;   // 0 .. 655359
    int which = idx >= 327680;
    int rem = which ? idx - 327680 : idx;
    const float* src = which ? slow : fast;
    float* dst = which ? xs : xf;
    int c = rem >> 12;
    int n = rem & 4095;
    int tt = n >> 10, hh = (n >> 5) & 31, ww = n & 31;
    int jy[4], jx[4]; float wy[4], wx[4];
    taps_down(hh, jy, wy);
    taps_down(ww, jx, wx);
    const float* base = src + ((c * 4 + tt) << 12);   // 64*64 plane
    float acc = 0.f;
#pragma unroll
    for (int a = 0; a < 4; ++a) {
        const float* row = base + (jy[a] << 6);
        float r = wx[0]*row[jx[0]] + wx[1]*row[jx[1]] + wx[2]*row[jx[2]] + wx[3]*row[jx[3]];
        acc += wy[a] * r;
    }
    dst[rem] = acc;
}

// ---------------- projections (transposed outputs [o][n]) ----------------
// grid (16 n-blocks, 10 o-slices of 4)
__global__ __launch_bounds__(TPB) void k_project(
        const float* __restrict__ xf,
        const float* __restrict__ gw, const float* __restrict__ gb,
        const float* __restrict__ thw, const float* __restrict__ thb,
        const float* __restrict__ phw, const float* __restrict__ phb,
        float* __restrict__ gxT, float* __restrict__ thetaT, float* __restrict__ phiT) {
    __shared__ float sW[960];   // mat*320 + oo*80 + c
    __shared__ float sB[12];
    int t = threadIdx.x;
    int o0 = blockIdx.y * 4;
    for (int i = t; i < 960; i += TPB) {          // FIX: strided loop (was if(t<960) with 256 threads)
        int mat = i / 320, rem = i % 320;
        int oo = rem / 80, c = rem % 80;
        const float* w = (mat == 0) ? gw : ((mat == 1) ? thw : phw);
        sW[i] = w[(o0 + oo) * 80 + c];
    }
    if (t < 12) {
        int mat = t / 4, oo = t % 4;
        const float* b = (mat == 0) ? gb : ((mat == 1) ? thb : phb);
        sB[t] = b[o0 + oo];
    }
    __syncthreads();
    int n = blockIdx.x * TPB + t;
    float x[80];
#pragma unroll
    for (int c = 0; c < 80; ++c) x[c] = xf[c * 4096 + n];
#pragma unroll
    for (int mat = 0; mat < 3; ++mat) {
        float* dst = (mat == 0) ? gxT : ((mat == 1) ? thetaT : phiT);
#pragma unroll
        for (int oo = 0; oo < 4; ++oo) {
            float acc = sB[mat * 4 + oo];
            const float4* w4 = (const float4*)&sW[mat * 320 + oo * 80];
#pragma unroll
            for (int cq = 0; cq < 20; ++cq) {
                float4 w = w4[cq];
                acc += w.x * x[cq*4] + w.y * x[cq*4+1] + w.z * x[cq*4+2] + w.w * x[cq*4+3];
            }
            dst[(o0 + oo) * 4096 + n] = acc;
        }
    }
}

// ---------------- fused attention: GEMM-tiled flash ----------------------
// grid (32 n-blocks of 128, 16 m-chunks of 256). Per chunk: 4 m-tiles of 64.
// LDS: ths [40][128] @0 (5120) | gst [40][68] @5120 (2720) | ES/phs @7840 (8192)
//   phs (during staging+F-GEMM): [40][64] unswizzled
//   Es  (after E-store): [64 m][32 granules of 4n], granule XOR-swizzled by (m&31)
#define ATT_GST 5120
#define ATT_ES  7840

__global__ __launch_bounds__(TPB) void k_attn(
        const float* __restrict__ thetaT, const float* __restrict__ phiT,
        const float* __restrict__ gxT,
        float* __restrict__ ypart, float* __restrict__ spart) {
    __shared__ float smem[16032];   // 64128 B
    int t = threadIdx.x;
    int n0 = blockIdx.x * 128;
    int ck = blockIdx.y;

    // F-GEMM mapping: 16 n-groups(8) x 16 m-groups(4)
    int ngrpF = t >> 4, mgrpF = t & 15;
    // Y-GEMM mapping: 32 n-groups(4) x 8 c-groups(5)
    int ngrpY = t >> 3, cgrpY = t & 7;

    // stage theta tile [40][128] once
    for (int i = t; i < 1280; i += TPB) {
        int c = i >> 5, iq = i & 31;
        *(float4*)(smem + c * 128 + iq * 4) =
            *(const float4*)(thetaT + c * 4096 + n0 + iq * 4);
    }

    float y[4][5];
    float s4[4] = {0.f, 0.f, 0.f, 0.f};
#pragma unroll
    for (int r = 0; r < 4; ++r)
#pragma unroll
        for (int u = 0; u < 5; ++u) y[r][u] = 0.f;

    for (int tile = 0; tile < 4; ++tile) {
        int m0 = ck * 256 + tile * 64;
        __syncthreads();   // prev Y-GEMM reads of ES/gst done (also covers theta staging)
        // stage phi -> phs [40][64], gx -> gst [40][68]
        for (int i = t; i < 640; i += TPB) {
            int c = i >> 4, mq = i & 15;
            *(float4*)(smem + ATT_ES + c * 64 + mq * 4) =
                *(const float4*)(phiT + c * 4096 + m0 + mq * 4);
            *(float4*)(smem + ATT_GST + c * 68 + mq * 4) =
                *(const float4*)(gxT + c * 4096 + m0 + mq * 4);
        }
        __syncthreads();   // staging visible

        // ---- F-GEMM: f[8][4] over c=40 ----
        float f[8][4];
#pragma unroll
        for (int r = 0; r < 8; ++r)
#pragma unroll
            for (int q = 0; q < 4; ++q) f[r][q] = 0.f;
        const float* thb = smem + ngrpF * 8;
        const float* phb = smem + ATT_ES + mgrpF * 4;
#pragma unroll 10
        for (int c = 0; c < 40; ++c) {
            float4 a0 = *(const float4*)(thb + c * 128);
            float4 a1 = *(const float4*)(thb + c * 128 + 4);
            float4 b  = *(const float4*)(phb + c * 64);
            float av[8] = {a0.x,a0.y,a0.z,a0.w,a1.x,a1.y,a1.z,a1.w};
            float bv[4] = {b.x,b.y,b.z,b.w};
#pragma unroll
            for (int r = 0; r < 8; ++r)
#pragma unroll
                for (int q = 0; q < 4; ++q) f[r][q] += av[r] * bv[q];
        }
        __syncthreads();   // phs reads done before E-store overwrites

        // ---- exp + store E to LDS (swizzled) ----
#pragma unroll
        for (int q = 0; q < 4; ++q) {
            int m = mgrpF * 4 + q;
            float4 e0, e1;
            e0.x = __expf(f[0][q]); e0.y = __expf(f[1][q]);
            e0.z = __expf(f[2][q]); e0.w = __expf(f[3][q]);
            e1.x = __expf(f[4][q]); e1.y = __expf(f[5][q]);
            e1.z = __expf(f[6][q]); e1.w = __expf(f[7][q]);
            int g0 = (ngrpF * 2)     ^ (m & 31);
            int g1 = (ngrpF * 2 + 1) ^ (m & 31);
            *(float4*)(smem + ATT_ES + m * 128 + g0 * 4) = e0;
            *(float4*)(smem + ATT_ES + m * 128 + g1 * 4) = e1;
        }
        __syncthreads();   // Es visible

        // ---- Y-GEMM: y[4][5] += E(4n x 64m) * G(64m x 5c) ----
        const float* gsb = smem + ATT_GST;
        int cbase = cgrpY * 5;
#pragma unroll 4
        for (int mi = 0; mi < 16; ++mi) {
            int mb = mi * 4;
            float ee[4][4];
#pragma unroll
            for (int j = 0; j < 4; ++j) {
                int m = mb + j;
                int g = ngrpY ^ (m & 31);
                *(float4*)ee[j] = *(const float4*)(smem + ATT_ES + m * 128 + g * 4);
            }
#pragma unroll
            for (int u = 0; u < 5; ++u) {
                float4 g = *(const float4*)(gsb + (cbase + u) * 68 + mb);
#pragma unroll
                for (int r = 0; r < 4; ++r)
                    y[r][u] += ee[0][r]*g.x + ee[1][r]*g.y + ee[2][r]*g.z + ee[3][r]*g.w;
            }
#pragma unroll
            for (int r = 0; r < 4; ++r)
                s4[r] += ee[0][r] + ee[1][r] + ee[2][r] + ee[3][r];
        }
    }

    // write out partials
    int nb = n0 + ngrpY * 4;
    float* yp = ypart + ((size_t)ck * 4096 + nb) * 40 + cgrpY * 5;
#pragma unroll
    for (int r = 0; r < 4; ++r)
#pragma unroll
        for (int u = 0; u < 5; ++u) yp[r * 40 + u] = y[r][u];
    if (cgrpY == 0) {
#pragma unroll
        for (int r = 0; r < 4; ++r) spart[ck * 4096 + nb + r] = s4[r];
    }
}

// ---------------- combine partials -> yfin[o][n] -------------------------
__global__ __launch_bounds__(TPB) void k_combine(
        const float* __restrict__ ypart, const float* __restrict__ spart,
        float* __restrict__ yfin) {
    int idx = blockIdx.x * TPB + threadIdx.x;   // 0..163839
    int o = idx >> 12;
    int n = idx & 4095;
    float ss = 0.f;
#pragma unroll
    for (int ck = 0; ck < 16; ++ck) ss += spart[ck * 4096 + n];
    float acc = 0.f;
#pragma unroll
    for (int ck = 0; ck < 16; ++ck) acc += ypart[(size_t)ck * 163840 + n * 40 + o];
    yfin[o * 4096 + n] = acc / ss;
}

// ---------------- wz proj + BatchNorm + slow-mult + upsample -------------
__device__ __forceinline__ void taps_up(int i, int* j0, int* j1, float* w0, float* w1) {
    if (i == 0)        { *j0 = 0;        *j1 = 0;          *w0 = 0.f;   *w1 = 1.f;   }
    else if (i == 63)  { *j0 = 31;       *j1 = 31;         *w0 = 1.f;   *w1 = 0.f;   }
    else if (i & 1)    { *j0 = i >> 1;   *j1 = (i>>1) + 1; *w0 = 0.75f; *w1 = 0.25f; }
    else               { *j0 = (i>>1)-1; *j1 = i >> 1;     *w0 = 0.25f; *w1 = 0.75f; }
}

__global__ __launch_bounds__(TPB) void k_bn_up(
        const float* __restrict__ yfin, const float* __restrict__ wzw,
        const float* __restrict__ wzb, const float* __restrict__ bng,
        const float* __restrict__ bnb, const float* __restrict__ xs,
        float* __restrict__ out) {
    __shared__ float4 wrow4[1024];   // 16 KB: wy row, then normalized z
    __shared__ float sred[8];
    int ch = blockIdx.x;
    int t = threadIdx.x;
    float w[40];
#pragma unroll
    for (int o = 0; o < 40; ++o) w[o] = wzw[ch * 40 + o];
    float bias = wzb[ch];
    float s1 = 0.f, s2 = 0.f;
#pragma unroll
    for (int k = 0; k < 4; ++k) {
        int i = k * TPB + t;
        float4 a = make_float4(bias, bias, bias, bias);
#pragma unroll 8
        for (int o = 0; o < 40; ++o) {
            float4 yv = *(const float4*)(yfin + o * 4096 + i * 4);
            a.x += w[o]*yv.x; a.y += w[o]*yv.y; a.z += w[o]*yv.z; a.w += w[o]*yv.w;
        }
        wrow4[i] = a;
        s1 += a.x + a.y + a.z + a.w;
        s2 += a.x*a.x + a.y*a.y + a.z*a.z + a.w*a.w;
    }
    // wave reduce
#pragma unroll
    for (int off = 32; off > 0; off >>= 1) {
        s1 += __shfl_down(s1, off);
        s2 += __shfl_down(s2, off);
    }
    int wid = t >> 6;
    if ((t & 63) == 0) { sred[wid] = s1; sred[4 + wid] = s2; }
    __syncthreads();
    float mean = (sred[0] + sred[1] + sred[2] + sred[3]) * (1.f / 4096.f);
    float var  = (sred[4] + sred[5] + sred[6] + sred[7]) * (1.f / 4096.f) - mean * mean;
    float inv = rsqrtf(var + 1e-5f);
    float sc = bng[ch] * inv;
    float sh = bnb[ch] - mean * sc;
    // normalize + multiply by x_slow, back into LDS
#pragma unroll
    for (int k = 0; k < 4; ++k) {
        int i = k * TPB + t;
        float4 a = wrow4[i];
        float4 xv = *(const float4*)(xs + ch * 4096 + i * 4);
        a.x = (a.x*sc + sh)*xv.x; a.y = (a.y*sc + sh)*xv.y;
        a.z = (a.z*sc + sh)*xv.z; a.w = (a.w*sc + sh)*xv.w;
        wrow4[i] = a;
    }
    __syncthreads();
    // upsample 32->64 from LDS
    const float* zs = (const float*)wrow4;
    int chbase = ch << 14;
#pragma unroll 4
    for (int k = 0; k < 64; ++k) {
        int p = k * TPB + t;          // 0..16383
        int tt = p >> 12, yy = (p >> 6) & 63, xx = p & 63;
        int jy0, jy1, jx0, jx1; float wy0, wy1, wx0, wx1;
        taps_up(yy, &jy0, &jy1, &wy0, &wy1);
        taps_up(xx, &jx0, &jx1, &wx0, &wx1);
        const float* pl = zs + tt * 1024;
        float r0 = wx0*pl[jy0*32 + jx0] + wx1*pl[jy0*32 + jx1];
        float r1 = wx0*pl[jy1*32 + jx0] + wx1*pl[jy1*32 + jx1];
        out[chbase + p] = wy0*r0 + wy1*r1;
    }
}

extern "C" void kernel_launch(void* const* d_in, const int* in_sizes, int n_in,
                              void* d_out, int out_size, void* d_ws, size_t ws_size,
                              hipStream_t stream) {
    const float* fast = (const float*)d_in[0];
    const float* slow = (const float*)d_in[1];
    const float* g_w  = (const float*)d_in[2];
    const float* g_b  = (const float*)d_in[3];
    const float* th_w = (const float*)d_in[4];
    const float* th_b = (const float*)d_in[5];
    const float* ph_w = (const float*)d_in[6];
    const float* ph_b = (const float*)d_in[7];
    const float* wz_w = (const float*)d_in[8];
    const float* wz_b = (const float*)d_in[9];
    const float* bn_g = (const float*)d_in[10];
    const float* bn_b = (const float*)d_in[11];
    float* out = (float*)d_out;
    float* ws  = (float*)d_ws;

    float* xf     = ws;
    float* xs     = ws + 327680;
    float* thetaT = ws + 655360;
    float* phiT   = ws + 819200;
    float* gxT    = ws + 983040;
    float* ypart  = ws + 1146880;
    float* spart  = ws + 3768320;
    float* yfin   = ws + 3833856;

    k_downsample<<<2560, TPB, 0, stream>>>(fast, slow, xf, xs);
    k_project<<<dim3(16, 10), TPB, 0, stream>>>(xf, g_w, g_b, th_w, th_b, ph_w, ph_b,
                                                gxT, thetaT, phiT);
    k_attn<<<dim3(32, 16), TPB, 0, stream>>>(thetaT, phiT, gxT, ypart, spart);
    k_combine<<<640, TPB, 0, stream>>>(ypart, spart, yfin);
    k_bn_up<<<80, TPB, 0, stream>>>(yfin, wz_w, wz_b, bn_g, bn_b, xs, out);
}